// Round 4
// baseline (5674.200 us; speedup 1.0000x reference)
//
#include <hip/hip_runtime.h>
#include <math.h>

#define EMBD 300
#define HROW 300     // bf16 h row stride (elements)
#define LDF  304     // fp32 junction-phase row stride
#define KEXT 320     // extended K: 300 h + 1 bias + 6 ee1 + 3 ee2 + 10 pad
#define TSTR 328     // LDS A-tile row stride (bf16), 656B: 16B-aligned, 2-way banks
#define BSTR 40      // LDS B row stride (bf16), 80B: 16B-aligned, 2-way banks
#define CE(a,b) (((a)+(b)-1)/(b))

typedef unsigned short bf16t;
typedef __attribute__((ext_vector_type(8))) short short8;
typedef __attribute__((ext_vector_type(4))) float f32x4;

__device__ inline float bf2f(bf16t v){
  union { unsigned u; float f; } x; x.u = ((unsigned)v) << 16; return x.f;
}
__device__ inline bf16t f2bf(float f){
  union { float f; unsigned u; } x; x.f = f;
  unsigned r = x.u + 0x7FFFu + ((x.u >> 16) & 1u);
  return (bf16t)(r >> 16);
}

// ---------------- utility / CSR kernels ----------------
__global__ void k_diag(float* out, int n, float v){
  int i = blockIdx.x*256 + threadIdx.x;
  if (i < n) out[i] = v;
}
__global__ void k_set_val(int* p, int n, int v){
  int i = blockIdx.x*256 + threadIdx.x;
  if (i < n) p[i] = v;
}
__global__ void k_count_src(const int* __restrict__ ei, int E, int* __restrict__ deg){
  int e = blockIdx.x*256 + threadIdx.x;
  if (e < E) atomicAdd(&deg[ei[e]], 1);
}
__global__ void k_dinv(const int* __restrict__ deg, float* __restrict__ dinv, int N){
  int i = blockIdx.x*256 + threadIdx.x;
  if (i < N) dinv[i] = 1.0f / sqrtf((float)(deg[i] + 1));   // +1 self-loop
}
__global__ void k_count_dst(const int* __restrict__ ei, int E, int* __restrict__ counts){
  int e = blockIdx.x*256 + threadIdx.x;
  if (e < E) atomicAdd(&counts[ei[E + e]], 1);
}
__global__ void k_count_ids(const int* __restrict__ ids, int n, int* __restrict__ counts){
  int i = blockIdx.x*256 + threadIdx.x;
  if (i < n) atomicAdd(&counts[ids[i]], 1);
}
__global__ void k_scan_block(const int* __restrict__ in, int M, int* __restrict__ out, int* __restrict__ bsum){
  __shared__ int s[256];
  int t = threadIdx.x, i = blockIdx.x*256 + t;
  int v = (i < M) ? in[i] : 0;
  s[t] = v; __syncthreads();
  for (int off = 1; off < 256; off <<= 1){
    int x = (t >= off) ? s[t-off] : 0;
    __syncthreads();
    s[t] += x;
    __syncthreads();
  }
  if (i < M) out[i] = s[t] - v;
  if (t == 255) bsum[blockIdx.x] = s[255];
}
__global__ void k_scan_sums(int* __restrict__ bsum, int B){   // B <= 1024
  __shared__ int s[1024];
  int t = threadIdx.x;
  int v = (t < B) ? bsum[t] : 0;
  s[t] = v; __syncthreads();
  for (int off = 1; off < 1024; off <<= 1){
    int x = (t >= off) ? s[t-off] : 0;
    __syncthreads();
    s[t] += x;
    __syncthreads();
  }
  if (t < B) bsum[t] = s[t] - v;
}
__global__ void k_scan_add(int* __restrict__ out, const int* __restrict__ bsum, int M){
  int i = blockIdx.x*256 + threadIdx.x;
  if (i < M) out[i] += bsum[blockIdx.x];
}
// entries payload: src | bt<<20 | bd<<23   (src < 2^20)
__global__ void k_fill_edges(const int* __restrict__ ei, const int* __restrict__ ea, int E, int N,
                             const int* __restrict__ offs, int* __restrict__ cur, int* __restrict__ entries){
  int e = blockIdx.x*256 + threadIdx.x;
  if (e < E){
    int s  = ei[e];
    int d  = ei[E + e];
    int bt = ea[2*e], bd = ea[2*e + 1];
    int pos = offs[d] + atomicAdd(&cur[d], 1);
    entries[pos] = s | (bt << 20) | (bd << 23);
  } else if (e < E + N){
    int i = e - E;                          // self-loop: bond type 4, dir 0
    int pos = offs[i] + atomicAdd(&cur[i], 1);
    entries[pos] = i | (4 << 20);
  }
}
__global__ void k_fill_rows(const int* __restrict__ ids, int n, const int* __restrict__ offs,
                            int* __restrict__ cur, int* __restrict__ entries){
  int i = blockIdx.x*256 + threadIdx.x;
  if (i < n){
    int g = ids[i];
    int pos = offs[g] + atomicAdd(&cur[g], 1);
    entries[pos] = i;
  }
}

// ---------------- model kernels ----------------
__global__ void k_init_h0(const int* __restrict__ x, const float* __restrict__ ae1,
                          const float* __restrict__ ae2, bf16t* __restrict__ h, int N){
  int i = blockIdx.x, t = threadIdx.x;
  int a = x[2*i], b = x[2*i + 1];
  const float* e1 = ae1 + (size_t)a*EMBD;
  const float* e2 = ae2 + (size_t)b*EMBD;
  bf16t* hr = h + (size_t)i*HROW;
  hr[t] = f2bf(e1[t] + e2[t]);
  int c = t + 256;
  if (c < EMBD) hr[c] = f2bf(e1[c] + e2[c]);
}

// extended weights: Wx[l][o][k], o,k in [0,KEXT)
// k<300: W[o][k]; k=300: b[o]; 301..306: ee1[k-301][o]; 307..309: ee2[k-307][o]; else 0
__global__ void k_wext(const float* __restrict__ W, const float* __restrict__ b,
                       const float* __restrict__ ee1, const float* __restrict__ ee2,
                       bf16t* __restrict__ out){
  int l = blockIdx.y, o = blockIdx.x, t = threadIdx.x;
  bf16t* d = out + ((size_t)l*KEXT + o)*KEXT;
  for (int k = t; k < KEXT; k += 256){
    float v = 0.f;
    if (o < EMBD){
      if      (k < EMBD)  v = W[(size_t)l*EMBD*EMBD + (size_t)o*EMBD + k];
      else if (k == 300)  v = b[l*EMBD + o];
      else if (k < 307)   v = ee1[((size_t)l*6 + (k-301))*EMBD + o];
      else if (k < 310)   v = ee2[((size_t)l*3 + (k-307))*EMBD + o];
    }
    d[k] = f2bf(v);
  }
}

__global__ void k_id_coef(float* coef){
  int c = blockIdx.x*256 + threadIdx.x;
  if (c >= EMBD) return;
  coef[c] = 1.f; coef[EMBD + c] = 0.f;
}
__global__ void k_bn_coef(const float* __restrict__ stats, const float* __restrict__ gamma,
                          const float* __restrict__ beta, float* __restrict__ coef, float invN){
  int c = blockIdx.x*256 + threadIdx.x;
  if (c >= EMBD) return;
  float mu  = stats[c]*invN;
  float var = stats[EMBD + c]*invN - mu*mu;
  float sc = gamma[c]*rsqrtf(var + 1e-5f);
  float sh = beta[c] - mu*sc;
  coef[c] = sc; coef[EMBD + c] = sh;
}

// ---- fused layer: gather(affine+relu prev) -> extended MFMA GEMM -> BN stats ----
// block = 64 dst rows; wave w owns rows w*16..w*16+15 (gather AND mfma A rows).
__global__ void __launch_bounds__(256)
k_layer(const bf16t* __restrict__ hPrev, const float* __restrict__ dinv,
        const int* __restrict__ offs, const int* __restrict__ counts,
        const int* __restrict__ entries, const bf16t* __restrict__ Wx,
        const float* __restrict__ coef, bf16t* __restrict__ hOut,
        int N, int relu, float* __restrict__ stats)
{
  __shared__ bf16t tile[64][TSTR];     // extended A tile (bf16)
  __shared__ bf16t Bs[KEXT][BSTR];     // current B k-slab
  __shared__ float sred[2*KEXT];       // per-block BN partial sums
  int tid = threadIdx.x;
  int wid = tid >> 6, lane = tid & 63;
  long row0 = (long)blockIdx.x * 64;

  for (int i = tid; i < 2*KEXT; i += 256) sred[i] = 0.f;

  // per-lane affine coef for its 5 gather columns
  float sc0=0,sc1=0,sc2=0,sc3=0,sc4=0, sh0=0,sh1=0,sh2=0,sh3=0,sh4=0;
  { int c;
    c = lane;       sc0 = coef[c]; sh0 = coef[EMBD+c];
    c = lane+64;    sc1 = coef[c]; sh1 = coef[EMBD+c];
    c = lane+128;   sc2 = coef[c]; sh2 = coef[EMBD+c];
    c = lane+192;   sc3 = coef[c]; sh3 = coef[EMBD+c];
    c = lane+256;   if (c < EMBD){ sc4 = coef[c]; sh4 = coef[EMBD+c]; }
  }

  // ---- phase 1: gather 16 rows per wave ----
  for (int rr = 0; rr < 16; rr++){
    int lr = wid*16 + rr;
    long g = row0 + lr;
    float a0=0,a1=0,a2=0,a3=0,a4=0;
    float t0=0,t1=0,t2=0,t3=0,t4=0,t5=0;
    float d0=0,d1=0,d2=0;
    float di = 0.f;
    if (g < N){
      int off = offs[g], cnt = counts[g];
      di = dinv[g];
      for (int j = 0; j < cnt; j++){
        int p = entries[off + j];
        int s = p & 0xFFFFF;
        int bt = (p >> 20) & 7, bd = (p >> 23) & 3;
        float w = dinv[s];
        const bf16t* ls = hPrev + (size_t)s*HROW;
        float x;
        x = sc0*bf2f(ls[lane      ]) + sh0; if (relu) x = fmaxf(x,0.f); a0 += w*x;
        x = sc1*bf2f(ls[lane + 64 ]) + sh1; if (relu) x = fmaxf(x,0.f); a1 += w*x;
        x = sc2*bf2f(ls[lane + 128]) + sh2; if (relu) x = fmaxf(x,0.f); a2 += w*x;
        x = sc3*bf2f(ls[lane + 192]) + sh3; if (relu) x = fmaxf(x,0.f); a3 += w*x;
        if (lane + 256 < EMBD){
          x = sc4*bf2f(ls[lane + 256]) + sh4; if (relu) x = fmaxf(x,0.f); a4 += w*x;
        }
        t0 += (bt==0)?w:0.f; t1 += (bt==1)?w:0.f; t2 += (bt==2)?w:0.f;
        t3 += (bt==3)?w:0.f; t4 += (bt==4)?w:0.f; t5 += (bt==5)?w:0.f;
        d0 += (bd==0)?w:0.f; d1 += (bd==1)?w:0.f; d2 += (bd==2)?w:0.f;
      }
    }
    tile[lr][lane      ] = f2bf(di*a0);
    tile[lr][lane + 64 ] = f2bf(di*a1);
    tile[lr][lane + 128] = f2bf(di*a2);
    tile[lr][lane + 192] = f2bf(di*a3);
    if (lane + 256 < EMBD) tile[lr][lane + 256] = f2bf(di*a4);
    if (lane < 20){
      float v = 0.f;
      if      (lane == 0) v = t0+t1+t2+t3+t4+t5;   // wsum (bias weight)
      else if (lane == 1) v = t0; else if (lane == 2) v = t1;
      else if (lane == 3) v = t2; else if (lane == 4) v = t3;
      else if (lane == 5) v = t4; else if (lane == 6) v = t5;
      else if (lane == 7) v = d0; else if (lane == 8) v = d1;
      else if (lane == 9) v = d2;
      tile[lr][EMBD + lane] = (lane < 10) ? f2bf(di*v) : (bf16t)0;
    }
  }

  // ---- phase 2: GEMM (wave: 16 rows x 320 cols) ----
  int m16 = lane & 15, koff = (lane >> 4) * 8;
  f32x4 acc[20];
  #pragma unroll
  for (int j = 0; j < 20; j++) acc[j] = (f32x4){0.f,0.f,0.f,0.f};

  for (int k0 = 0; k0 < KEXT; k0 += 32){
    __syncthreads();
    for (int idx = tid; idx < 1280; idx += 256){
      int o = idx >> 2, q = (idx & 3) * 8;
      *(uint4*)&Bs[o][q] = *(const uint4*)(Wx + (size_t)o*KEXT + k0 + q);
    }
    __syncthreads();
    short8 af = *(const short8*)&tile[wid*16 + m16][k0 + koff];
    #pragma unroll
    for (int j = 0; j < 20; j++){
      short8 bfr = *(const short8*)&Bs[j*16 + m16][koff];
      acc[j] = __builtin_amdgcn_mfma_f32_16x16x32_bf16(af, bfr, acc[j], 0, 0, 0);
    }
  }

  // ---- epilogue: store + BN stats ----
  int cr = (lane >> 4) * 4;
  #pragma unroll
  for (int j = 0; j < 20; j++){
    int col = j*16 + m16;
    float s = 0.f, q = 0.f;
    #pragma unroll
    for (int r = 0; r < 4; r++){
      long row = row0 + wid*16 + cr + r;
      float v = acc[j][r];
      if (col < EMBD && row < N) hOut[row*HROW + col] = f2bf(v);
      s += v; q += v*v;
    }
    s += __shfl_xor(s, 16, 64); s += __shfl_xor(s, 32, 64);
    q += __shfl_xor(q, 16, 64); q += __shfl_xor(q, 32, 64);
    if ((lane >> 4) == 0 && col < EMBD){
      atomicAdd(&sred[col], s);
      atomicAdd(&sred[KEXT + col], q);
    }
  }
  __syncthreads();
  for (int c = tid; c < EMBD; c += 256){
    atomicAdd(&stats[c], sred[c]);
    atomicAdd(&stats[EMBD + c], sred[KEXT + c]);
  }
}

__global__ void k_pool_bf(const bf16t* __restrict__ h, const int* __restrict__ offs,
                          const int* __restrict__ counts, const int* __restrict__ entries,
                          float* __restrict__ out, int M){
  int g = blockIdx.x, t = threadIdx.x, c1 = t + 256;
  int off = offs[g], cnt = counts[g];
  float a0 = 0.f, a1 = 0.f;
  for (int j = 0; j < cnt; j++){
    int r = entries[off + j];
    const bf16t* hr = h + (size_t)r*HROW;
    a0 += bf2f(hr[t]);
    if (c1 < EMBD) a1 += bf2f(hr[c1]);
  }
  float inv = 1.0f / fmaxf((float)cnt, 1.0f);
  float* o = out + (size_t)g*LDF;
  o[t] = a0*inv;
  if (c1 < EMBD) o[c1] = a1*inv;
}
__global__ void k_pool_f32(const float* __restrict__ h, const int* __restrict__ offs,
                           const int* __restrict__ counts, const int* __restrict__ entries,
                           float* __restrict__ out, int M){
  int g = blockIdx.x, t = threadIdx.x, c1 = t + 256;
  int off = offs[g], cnt = counts[g];
  float a0 = 0.f, a1 = 0.f;
  for (int j = 0; j < cnt; j++){
    int r = entries[off + j];
    const float* hr = h + (size_t)r*LDF;
    a0 += hr[t];
    if (c1 < EMBD) a1 += hr[c1];
  }
  float inv = 1.0f / fmaxf((float)cnt, 1.0f);
  float* o = out + (size_t)g*LDF;
  o[t] = a0*inv;
  if (c1 < EMBD) o[c1] = a1*inv;
}

// pooled rows: v = sc[c]*v + sh[c]  (last-layer BN folded past the mean-pool)
__global__ void k_affine_rows(float* __restrict__ rows, const float* __restrict__ coef, int M){
  int g = blockIdx.x, t = threadIdx.x, c1 = t + 256;
  float* r = rows + (size_t)g*LDF;
  r[t] = coef[t]*r[t] + coef[EMBD + t];
  if (c1 < EMBD) r[c1] = coef[c1]*r[c1] + coef[EMBD + c1];
}

__global__ void k_mask(float* __restrict__ j, const float* __restrict__ mask,
                       const float* __restrict__ memb, int M){
  int i = blockIdx.x;
  if (mask[i] <= 0.5f) return;
  int t = threadIdx.x, c1 = t + 256;
  float* jr = j + (size_t)i*LDF;
  jr[t] = memb[t];
  if (c1 < EMBD) jr[c1] = memb[c1];
}

__global__ void k_l2norm(float* __restrict__ f, int M){
  int g = blockIdx.x, t = threadIdx.x, c1 = t + 256;
  float* fr = f + (size_t)g*LDF;
  float v0 = fr[t];
  float v1 = (c1 < EMBD) ? fr[c1] : 0.f;
  float ss = v0*v0 + v1*v1;
  #pragma unroll
  for (int o = 32; o > 0; o >>= 1) ss += __shfl_down(ss, o, 64);
  __shared__ float red[4];
  int wid = t >> 6, lane = t & 63;
  if (lane == 0) red[wid] = ss;
  __syncthreads();
  if (t == 0) red[0] = 1.0f / fmaxf(sqrtf(red[0]+red[1]+red[2]+red[3]), 1e-12f);
  __syncthreads();
  float inv = red[0];
  fr[t] = v0*inv;
  if (c1 < EMBD) fr[c1] = v1*inv;
}

// fp32 GEMM for the small junction/logits matmuls
__global__ void __launch_bounds__(256)
k_gemm(const float* __restrict__ A, int lda, const float* __restrict__ W, int ldw,
       const float* __restrict__ bias, const float* __restrict__ e1, const float* __restrict__ e2,
       float* __restrict__ C, int ldc, int M, int Ncols, int K, int relu, float scale){
  __shared__ float As[16][68];
  __shared__ float Ws[16][68];
  int row0 = blockIdx.y * 64, col0 = blockIdx.x * 64;
  int tid = threadIdx.x;
  int tx = tid & 15, ty = tid >> 4;
  float acc[4][4] = {};
  for (int k0 = 0; k0 < K; k0 += 16){
    int r  = tid >> 2;
    int kk = (tid & 3) * 4;
    int gk = k0 + kk;
    float v[4] = {0.f,0.f,0.f,0.f};
    int gr = row0 + r;
    if (gr < M){
      if (gk + 3 < K){ float4 f = *(const float4*)(A + (size_t)gr*lda + gk); v[0]=f.x;v[1]=f.y;v[2]=f.z;v[3]=f.w; }
      else for (int j = 0; j < 4; j++) if (gk + j < K) v[j] = A[(size_t)gr*lda + gk + j];
    }
    As[kk+0][r]=v[0]; As[kk+1][r]=v[1]; As[kk+2][r]=v[2]; As[kk+3][r]=v[3];
    float w[4] = {0.f,0.f,0.f,0.f};
    int o = col0 + r;
    if (o < Ncols){
      if (gk + 3 < K){ float4 f = *(const float4*)(W + (size_t)o*ldw + gk); w[0]=f.x;w[1]=f.y;w[2]=f.z;w[3]=f.w; }
      else for (int j = 0; j < 4; j++) if (gk + j < K) w[j] = W[(size_t)o*ldw + gk + j];
    }
    Ws[kk+0][r]=w[0]; Ws[kk+1][r]=w[1]; Ws[kk+2][r]=w[2]; Ws[kk+3][r]=w[3];
    __syncthreads();
    #pragma unroll
    for (int k = 0; k < 16; k++){
      float4 a4 = *(const float4*)&As[k][ty*4];
      float4 b4 = *(const float4*)&Ws[k][tx*4];
      float a[4] = {a4.x,a4.y,a4.z,a4.w};
      float b[4] = {b4.x,b4.y,b4.z,b4.w};
      #pragma unroll
      for (int i = 0; i < 4; i++)
        #pragma unroll
        for (int j = 0; j < 4; j++) acc[i][j] += a[i]*b[j];
    }
    __syncthreads();
  }
  #pragma unroll
  for (int i = 0; i < 4; i++){
    int rr = row0 + ty*4 + i;
    if (rr >= M) continue;
    #pragma unroll
    for (int j = 0; j < 4; j++){
      int cc = col0 + tx*4 + j;
      if (cc >= Ncols) continue;
      float v = acc[i][j];
      if (bias) v += bias[cc];
      if (e1)   v += e1[cc];
      if (e2)   v += e2[cc];
      v *= scale;
      if (relu) v = fmaxf(v, 0.f);
      C[(size_t)rr*ldc + cc] = v;
    }
  }
}

// ---------------- host side ----------------
static inline void scan_excl(const int* counts, int M, int* offs, int* bsum, hipStream_t s){
  int B = CE(M, 256);
  k_scan_block<<<B,256,0,s>>>(counts, M, offs, bsum);
  k_scan_sums<<<1,1024,0,s>>>(bsum, B);
  k_scan_add<<<B,256,0,s>>>(offs, bsum, M);
}
static inline void gemm_f32(const float* A,int lda,const float* W,int ldw,
                            const float* bias,const float* e1,const float* e2,
                            float* C,int ldc,int M,int Ncols,int K,
                            int relu,float scale,hipStream_t s){
  dim3 grid(CE(Ncols,64), CE(M,64));
  k_gemm<<<grid,256,0,s>>>(A,lda,W,ldw,bias,e1,e2,C,ldc,M,Ncols,K,relu,scale);
}

extern "C" void kernel_launch(void* const* d_in, const int* in_sizes, int n_in,
                              void* d_out, int out_size, void* d_ws, size_t ws_size,
                              hipStream_t stream) {
  const int*   batch_x   = (const int*)d_in[0];
  const int*   batch_ei  = (const int*)d_in[1];
  const int*   batch_ea  = (const int*)d_in[2];
  const int*   batch_gid = (const int*)d_in[3];
  const int*   frag_x    = (const int*)d_in[4];
  const int*   frag_ei   = (const int*)d_in[5];
  const int*   frag_ea   = (const int*)d_in[6];
  const int*   frag_jid  = (const int*)d_in[7];
  const int*   jct_gid   = (const int*)d_in[8];
  const float* jct_mask  = (const float*)d_in[9];
  const float* ae1       = (const float*)d_in[10];
  const float* ae2       = (const float*)d_in[11];
  const float* gnn_W     = (const float*)d_in[12];
  const float* gnn_b     = (const float*)d_in[13];
  const float* gnn_ee1   = (const float*)d_in[14];
  const float* gnn_ee2   = (const float*)d_in[15];
  const float* bn_gamma  = (const float*)d_in[16];
  const float* bn_beta   = (const float*)d_in[17];
  const float* jct_W     = (const float*)d_in[18];
  const float* jct_b     = (const float*)d_in[19];
  const float* jct_ee1   = (const float*)d_in[20];
  const float* jct_ee2   = (const float*)d_in[21];
  const float* mask_emb  = (const float*)d_in[22];

  const int N = in_sizes[0] / 2;       // 200000
  const int E = in_sizes[1] / 2;       // 400000
  const int NG = 1024, NJ = 8192;

  // workspace carve-up (~249 MB)
  size_t off = 0;
  char* base = (char*)d_ws;
  auto carve = [&](size_t bytes) -> void* {
    void* p = base + off;
    off += (bytes + 255) & ~(size_t)255;
    return p;
  };
  bf16t* hA      = (bf16t*)carve((size_t)N * HROW * 2);
  bf16t* hB      = (bf16t*)carve((size_t)N * HROW * 2);
  float* dinv    = (float*)carve((size_t)N * 4);
  int*   degcnt  = (int*)  carve((size_t)N * 4);
  int*   cursor  = degcnt;                       // alias: dead after k_dinv
  int*   counts  = (int*)  carve((size_t)N * 4);
  int*   offs    = (int*)  carve((size_t)(N + 1) * 4);
  int*   entries = (int*)  carve((size_t)(E + N) * 4);
  int*   bsum    = (int*)  carve(1024 * 4);
  float* stats   = (float*)carve(2 * EMBD * 4);
  float* coef    = (float*)carve(2 * EMBD * 4);
  float* idcoef  = (float*)carve(2 * EMBD * 4);
  bf16t* wext    = (bf16t*)carve((size_t)5 * KEXT * KEXT * 2);
  float* f0      = (float*)carve((size_t)NG * LDF * 4);
  float* f1      = (float*)carve((size_t)NG * LDF * 4);
  size_t required = off;
  // junction-phase fp32 buffers alias hA (dead after the last k_layer reads it)
  float* g0      = (float*)hA;
  float* t1      = (float*)((char*)hA + ((size_t)16 << 20));
  float* t2      = (float*)((char*)hA + ((size_t)32 << 20));
  (void)n_in;

  if (ws_size < required || d_ws == nullptr){
    float v = 1.0e6f + (float)(ws_size >> 20) * 1000.0f;   // encode ws MB in absmax
    k_diag<<<CE(out_size,256),256,0,stream>>>((float*)d_out, out_size, v);
    return;
  }

  // one-time prep: extended bf16 weights, identity coef
  { dim3 g(KEXT, 5); k_wext<<<g,256,0,stream>>>(gnn_W, gnn_b, gnn_ee1, gnn_ee2, wext); }
  k_id_coef<<<CE(EMBD,256),256,0,stream>>>(idcoef);

  const int LBLK = CE(N, 64);   // fused-layer grid

  for (int br = 0; br < 2; br++){
    const int* x  = br ? frag_x  : batch_x;
    const int* ei = br ? frag_ei : batch_ei;
    const int* ea = br ? frag_ea : batch_ea;

    // degree (by src, +1 self-loop) -> dinv
    hipMemsetAsync(degcnt, 0, (size_t)N*4, stream);
    k_count_src<<<CE(E,256),256,0,stream>>>(ei, E, degcnt);
    k_dinv<<<CE(N,256),256,0,stream>>>(degcnt, dinv, N);

    // dst-CSR over E real edges + N self-loops (layer-invariant)
    k_set_val<<<CE(N,256),256,0,stream>>>(counts, N, 1);
    k_count_dst<<<CE(E,256),256,0,stream>>>(ei, E, counts);
    scan_excl(counts, N, offs, bsum, stream);
    hipMemsetAsync(cursor, 0, (size_t)N*4, stream);
    k_fill_edges<<<CE(E+N,256),256,0,stream>>>(ei, ea, E, N, offs, cursor, entries);

    // h0 = ae1[x0] + ae2[x1]
    k_init_h0<<<N,256,0,stream>>>(x, ae1, ae2, hA, N);

    // 5 fused layers, ping-pong hA <-> hB; final lin output lands in hB
    for (int l = 0; l < 5; l++){
      const bf16t* src = (l & 1) ? hB : hA;
      bf16t*       dst = (l & 1) ? hA : hB;
      hipMemsetAsync(stats, 0, 2*EMBD*4, stream);
      k_layer<<<LBLK,256,0,stream>>>(src, dinv, offs, counts, entries,
                                     wext + (size_t)l*KEXT*KEXT,
                                     (l == 0) ? idcoef : coef, dst,
                                     N, (l > 0) ? 1 : 0, stats);
      k_bn_coef<<<CE(EMBD,256),256,0,stream>>>(stats, bn_gamma + l*EMBD, bn_beta + l*EMBD,
                                               coef, 1.0f/(float)N);
    }
    // hB holds raw layer-4 lin output; coef holds its BN affine (no relu on last layer):
    // BN commutes with mean-pool -> apply affine on pooled rows.

    if (br == 0){
      hipMemsetAsync(counts, 0, (size_t)NG*4, stream);
      k_count_ids<<<CE(N,256),256,0,stream>>>(batch_gid, N, counts);
      scan_excl(counts, NG, offs, bsum, stream);
      hipMemsetAsync(cursor, 0, (size_t)NG*4, stream);
      k_fill_rows<<<CE(N,256),256,0,stream>>>(batch_gid, N, offs, cursor, entries);
      k_pool_bf<<<NG,256,0,stream>>>(hB, offs, counts, entries, g0, NG);
      k_affine_rows<<<NG,256,0,stream>>>(g0, coef, NG);
      gemm_f32(g0, LDF, jct_W, EMBD, jct_b,
               jct_ee1 + 4*EMBD, jct_ee2,
               t1, LDF, NG, EMBD, EMBD, 1, 1.0f, stream);
      gemm_f32(t1, LDF, jct_W + EMBD*EMBD, EMBD, jct_b + EMBD,
               jct_ee1 + 6*EMBD + 4*EMBD, jct_ee2 + 3*EMBD,
               f0, LDF, NG, EMBD, EMBD, 0, 1.0f, stream);
      k_l2norm<<<NG,256,0,stream>>>(f0, NG);
    } else {
      hipMemsetAsync(counts, 0, (size_t)NJ*4, stream);
      k_count_ids<<<CE(N,256),256,0,stream>>>(frag_jid, N, counts);
      scan_excl(counts, NJ, offs, bsum, stream);
      hipMemsetAsync(cursor, 0, (size_t)NJ*4, stream);
      k_fill_rows<<<CE(N,256),256,0,stream>>>(frag_jid, N, offs, cursor, entries);
      k_pool_bf<<<NJ,256,0,stream>>>(hB, offs, counts, entries, t1, NJ);
      k_affine_rows<<<NJ,256,0,stream>>>(t1, coef, NJ);
      k_mask<<<NJ,256,0,stream>>>(t1, jct_mask, mask_emb, NJ);
      gemm_f32(t1, LDF, jct_W, EMBD, jct_b,
               jct_ee1 + 4*EMBD, jct_ee2,
               t2, LDF, NJ, EMBD, EMBD, 1, 1.0f, stream);
      gemm_f32(t2, LDF, jct_W + EMBD*EMBD, EMBD, jct_b + EMBD,
               jct_ee1 + 6*EMBD + 4*EMBD, jct_ee2 + 3*EMBD,
               t1, LDF, NJ, EMBD, EMBD, 0, 1.0f, stream);
      hipMemsetAsync(counts, 0, (size_t)NG*4, stream);
      k_count_ids<<<CE(NJ,256),256,0,stream>>>(jct_gid, NJ, counts);
      scan_excl(counts, NG, offs, bsum, stream);
      hipMemsetAsync(cursor, 0, (size_t)NG*4, stream);
      k_fill_rows<<<CE(NJ,256),256,0,stream>>>(jct_gid, NJ, offs, cursor, entries);
      k_pool_f32<<<NG,256,0,stream>>>(t1, offs, counts, entries, f1, NG);
      k_l2norm<<<NG,256,0,stream>>>(f1, NG);
    }
  }

  // logits = (f0 @ f1^T) / TEMP
  gemm_f32(f0, LDF, f1, LDF, nullptr, nullptr, nullptr,
           (float*)d_out, 1024, NG, NG, EMBD, 0, 25.0f, stream);
}

// Round 5
// 4780.499 us; speedup vs baseline: 1.1869x; 1.1869x over previous
//
#include <hip/hip_runtime.h>
#include <math.h>

#define EMBD 300
#define HROW 300     // bf16 h row stride (elements)
#define LDF  304     // fp32 junction-phase row stride
#define KEXT 320     // extended K: 300 h + 1 bias + 6 ee1 + 3 ee2 + 10 pad
#define TSTR 328     // LDS A-tile row stride (bf16): 656B, 16B-aligned
#define BSTR 40      // LDS B row stride (bf16): 80B, 16B-aligned, 2-way banks
#define BCH  80      // B cols per jt chunk (4 chunks of 80 = 320)
#define MAXE 8       // edge-preload batch (cnt = 1 + Poisson(2); P(>8) ~ 1e-3)
#define CE(a,b) (((a)+(b)-1)/(b))

typedef unsigned short bf16t;
typedef __attribute__((ext_vector_type(8))) short short8;
typedef __attribute__((ext_vector_type(4))) float f32x4;

__device__ inline float bf2f(bf16t v){
  union { unsigned u; float f; } x; x.u = ((unsigned)v) << 16; return x.f;
}
__device__ inline bf16t f2bf(float f){
  union { float f; unsigned u; } x; x.f = f;
  unsigned r = x.u + 0x7FFFu + ((x.u >> 16) & 1u);
  return (bf16t)(r >> 16);
}

// ---------------- utility / CSR kernels ----------------
__global__ void k_diag(float* out, int n, float v){
  int i = blockIdx.x*256 + threadIdx.x;
  if (i < n) out[i] = v;
}
__global__ void k_set_val(int* p, int n, int v){
  int i = blockIdx.x*256 + threadIdx.x;
  if (i < n) p[i] = v;
}
__global__ void k_count_src(const int* __restrict__ ei, int E, int* __restrict__ deg){
  int e = blockIdx.x*256 + threadIdx.x;
  if (e < E) atomicAdd(&deg[ei[e]], 1);
}
__global__ void k_dinv(const int* __restrict__ deg, float* __restrict__ dinv, int N){
  int i = blockIdx.x*256 + threadIdx.x;
  if (i < N) dinv[i] = 1.0f / sqrtf((float)(deg[i] + 1));   // +1 self-loop
}
__global__ void k_count_dst(const int* __restrict__ ei, int E, int* __restrict__ counts){
  int e = blockIdx.x*256 + threadIdx.x;
  if (e < E) atomicAdd(&counts[ei[E + e]], 1);
}
__global__ void k_count_ids(const int* __restrict__ ids, int n, int* __restrict__ counts){
  int i = blockIdx.x*256 + threadIdx.x;
  if (i < n) atomicAdd(&counts[ids[i]], 1);
}
__global__ void k_scan_block(const int* __restrict__ in, int M, int* __restrict__ out, int* __restrict__ bsum){
  __shared__ int s[256];
  int t = threadIdx.x, i = blockIdx.x*256 + t;
  int v = (i < M) ? in[i] : 0;
  s[t] = v; __syncthreads();
  for (int off = 1; off < 256; off <<= 1){
    int x = (t >= off) ? s[t-off] : 0;
    __syncthreads();
    s[t] += x;
    __syncthreads();
  }
  if (i < M) out[i] = s[t] - v;
  if (t == 255) bsum[blockIdx.x] = s[255];
}
__global__ void k_scan_sums(int* __restrict__ bsum, int B){   // B <= 1024
  __shared__ int s[1024];
  int t = threadIdx.x;
  int v = (t < B) ? bsum[t] : 0;
  s[t] = v; __syncthreads();
  for (int off = 1; off < 1024; off <<= 1){
    int x = (t >= off) ? s[t-off] : 0;
    __syncthreads();
    s[t] += x;
    __syncthreads();
  }
  if (t < B) bsum[t] = s[t] - v;
}
__global__ void k_scan_add(int* __restrict__ out, const int* __restrict__ bsum, int M){
  int i = blockIdx.x*256 + threadIdx.x;
  if (i < M) out[i] += bsum[blockIdx.x];
}
// entries payload: src | bt<<20 | bd<<23   (src < 2^20)
__global__ void k_fill_edges(const int* __restrict__ ei, const int* __restrict__ ea, int E, int N,
                             const int* __restrict__ offs, int* __restrict__ cur, int* __restrict__ entries){
  int e = blockIdx.x*256 + threadIdx.x;
  if (e < E){
    int s  = ei[e];
    int d  = ei[E + e];
    int bt = ea[2*e], bd = ea[2*e + 1];
    int pos = offs[d] + atomicAdd(&cur[d], 1);
    entries[pos] = s | (bt << 20) | (bd << 23);
  } else if (e < E + N){
    int i = e - E;                          // self-loop: bond type 4, dir 0
    int pos = offs[i] + atomicAdd(&cur[i], 1);
    entries[pos] = i | (4 << 20);
  }
}
__global__ void k_fill_rows(const int* __restrict__ ids, int n, const int* __restrict__ offs,
                            int* __restrict__ cur, int* __restrict__ entries){
  int i = blockIdx.x*256 + threadIdx.x;
  if (i < n){
    int g = ids[i];
    int pos = offs[g] + atomicAdd(&cur[g], 1);
    entries[pos] = i;
  }
}

// ---------------- model kernels ----------------
__global__ void k_init_h0(const int* __restrict__ x, const float* __restrict__ ae1,
                          const float* __restrict__ ae2, bf16t* __restrict__ h, int N){
  int i = blockIdx.x, t = threadIdx.x;
  int a = x[2*i], b = x[2*i + 1];
  const float* e1 = ae1 + (size_t)a*EMBD;
  const float* e2 = ae2 + (size_t)b*EMBD;
  bf16t* hr = h + (size_t)i*HROW;
  hr[t] = f2bf(e1[t] + e2[t]);
  int c = t + 256;
  if (c < EMBD) hr[c] = f2bf(e1[c] + e2[c]);
}

// extended weights: Wx[l][o][k], o,k in [0,KEXT)
// k<300: W[o][k]; k=300: b[o]; 301..306: ee1[k-301][o]; 307..309: ee2[k-307][o]; else 0
__global__ void k_wext(const float* __restrict__ W, const float* __restrict__ b,
                       const float* __restrict__ ee1, const float* __restrict__ ee2,
                       bf16t* __restrict__ out){
  int l = blockIdx.y, o = blockIdx.x, t = threadIdx.x;
  bf16t* d = out + ((size_t)l*KEXT + o)*KEXT;
  for (int k = t; k < KEXT; k += 256){
    float v = 0.f;
    if (o < EMBD){
      if      (k < EMBD)  v = W[(size_t)l*EMBD*EMBD + (size_t)o*EMBD + k];
      else if (k == 300)  v = b[l*EMBD + o];
      else if (k < 307)   v = ee1[((size_t)l*6 + (k-301))*EMBD + o];
      else if (k < 310)   v = ee2[((size_t)l*3 + (k-307))*EMBD + o];
    }
    d[k] = f2bf(v);
  }
}

__global__ void k_id_coef(float* coef){
  int c = blockIdx.x*256 + threadIdx.x;
  if (c >= EMBD) return;
  coef[c] = 1.f; coef[EMBD + c] = 0.f;
}
__global__ void k_bn_coef(const float* __restrict__ stats, const float* __restrict__ gamma,
                          const float* __restrict__ beta, float* __restrict__ coef, float invN){
  int c = blockIdx.x*256 + threadIdx.x;
  if (c >= EMBD) return;
  float mu  = stats[c]*invN;
  float var = stats[EMBD + c]*invN - mu*mu;
  float sc = gamma[c]*rsqrtf(var + 1e-5f);
  float sh = beta[c] - mu*sc;
  coef[c] = sc; coef[EMBD + c] = sh;
}

// ---- fused layer: gather(affine+relu prev) -> extended MFMA GEMM -> BN stats ----
// block = 64 dst rows; wave w gathers rows w*16..w*16+15 = its own MFMA A rows.
__global__ void __launch_bounds__(256)
k_layer(const bf16t* __restrict__ hPrev, const float* __restrict__ dinv,
        const int* __restrict__ offs, const int* __restrict__ counts,
        const int* __restrict__ entries, const bf16t* __restrict__ Wx,
        const float* __restrict__ coef, bf16t* __restrict__ hOut,
        int N, int relu, float* __restrict__ stats)
{
  __shared__ bf16t tile[64][TSTR];     // 42.0 KB extended A tile
  __shared__ bf16t Bs[BCH][BSTR];      //  6.4 KB B chunk (80 cols x 32 k)
  __shared__ float sred[2*KEXT];       //  2.6 KB BN partials
  int tid = threadIdx.x;
  int wid = tid >> 6, lane = tid & 63;
  long row0 = (long)blockIdx.x * 64;

  for (int i = tid; i < 2*KEXT; i += 256) sred[i] = 0.f;

  // per-lane BN affine coef for its 5 gather columns
  float sc0=0,sc1=0,sc2=0,sc3=0,sc4=0, sh0=0,sh1=0,sh2=0,sh3=0,sh4=0;
  { int c;
    c = lane;       sc0 = coef[c]; sh0 = coef[EMBD+c];
    c = lane+64;    sc1 = coef[c]; sh1 = coef[EMBD+c];
    c = lane+128;   sc2 = coef[c]; sh2 = coef[EMBD+c];
    c = lane+192;   sc3 = coef[c]; sh3 = coef[EMBD+c];
    c = lane+256;   if (c < EMBD){ sc4 = coef[c]; sh4 = coef[EMBD+c]; }
  }
  bool lane4ok = (lane + 256) < EMBD;
  // per-lane extended-scalar selector (lane0: sum w; 1-6: bond type; 7-9: bond dir)
  bool is_w = (lane == 0);
  int bsel = (lane >= 1 && lane <= 6) ? (lane - 1) : -1;
  int dsel = (lane >= 7 && lane <= 9) ? (lane - 7) : -1;

  // ---- phase 1: gather 16 rows per wave (edge-batched for MLP) ----
  for (int rr = 0; rr < 16; rr++){
    int lr = wid*16 + rr;
    long g = row0 + lr;
    float a0=0,a1=0,a2=0,a3=0,a4=0, esum=0;
    float di = 0.f;
    if (g < N){
      int off = offs[g], cnt = counts[g];
      di = dinv[g];
      for (int j0 = 0; j0 < cnt; j0 += MAXE){
        int m = cnt - j0; if (m > MAXE) m = MAXE;
        int pj[MAXE]; float wj[MAXE];
        #pragma unroll
        for (int j = 0; j < MAXE; j++) if (j < m) pj[j] = entries[off + j0 + j];
        #pragma unroll
        for (int j = 0; j < MAXE; j++) if (j < m) wj[j] = dinv[pj[j] & 0xFFFFF];
        #pragma unroll
        for (int j = 0; j < MAXE; j++) if (j < m){
          int p = pj[j];
          int s = p & 0xFFFFF;
          float w = wj[j];
          const bf16t* ls = hPrev + (size_t)s*HROW;
          float x;
          x = sc0*bf2f(ls[lane      ]) + sh0; if (relu) x = fmaxf(x,0.f); a0 += w*x;
          x = sc1*bf2f(ls[lane + 64 ]) + sh1; if (relu) x = fmaxf(x,0.f); a1 += w*x;
          x = sc2*bf2f(ls[lane + 128]) + sh2; if (relu) x = fmaxf(x,0.f); a2 += w*x;
          x = sc3*bf2f(ls[lane + 192]) + sh3; if (relu) x = fmaxf(x,0.f); a3 += w*x;
          if (lane4ok){
            x = sc4*bf2f(ls[lane + 256]) + sh4; if (relu) x = fmaxf(x,0.f); a4 += w*x;
          }
          int bt = (p >> 20) & 7, bd = (p >> 23) & 3;
          bool take = is_w || (bt == bsel) || (bd == dsel);
          esum += take ? w : 0.f;
        }
      }
    }
    tile[lr][lane      ] = f2bf(di*a0);
    tile[lr][lane + 64 ] = f2bf(di*a1);
    tile[lr][lane + 128] = f2bf(di*a2);
    tile[lr][lane + 192] = f2bf(di*a3);
    if (lane4ok) tile[lr][lane + 256] = f2bf(di*a4);
    if (lane < 20) tile[lr][EMBD + lane] = (lane < 10) ? f2bf(di*esum) : (bf16t)0;
  }

  // A fragments: this wave's own tile rows -> registers (no barrier needed)
  int m16 = lane & 15, koff = (lane >> 4) * 8;
  short8 afr[10];
  #pragma unroll
  for (int k = 0; k < 10; k++)
    afr[k] = *(const short8*)&tile[wid*16 + m16][k*32 + koff];

  // ---- phase 2: GEMM over 4 col-chunks of 80 ----
  int cr = (lane >> 4) * 4;
  for (int jt = 0; jt < 4; jt++){
    f32x4 acc[5];
    #pragma unroll
    for (int j = 0; j < 5; j++) acc[j] = (f32x4){0.f,0.f,0.f,0.f};
    for (int k0 = 0; k0 < 10; k0++){
      __syncthreads();
      for (int idx = tid; idx < 320; idx += 256){
        int o = idx >> 2, q = (idx & 3) * 8;
        *(uint4*)&Bs[o][q] = *(const uint4*)(Wx + (size_t)(jt*BCH + o)*KEXT + k0*32 + q);
      }
      __syncthreads();
      #pragma unroll
      for (int j = 0; j < 5; j++){
        short8 bfr = *(const short8*)&Bs[j*16 + m16][koff];
        acc[j] = __builtin_amdgcn_mfma_f32_16x16x32_bf16(afr[k0], bfr, acc[j], 0, 0, 0);
      }
    }
    // epilogue for these 80 cols: store + BN partials
    #pragma unroll
    for (int j = 0; j < 5; j++){
      int col = jt*BCH + j*16 + m16;
      float s = 0.f, q = 0.f;
      #pragma unroll
      for (int r = 0; r < 4; r++){
        long row = row0 + wid*16 + cr + r;
        float v = acc[j][r];
        if (col < EMBD && row < N) hOut[row*HROW + col] = f2bf(v);
        s += v; q += v*v;
      }
      s += __shfl_xor(s, 16, 64); s += __shfl_xor(s, 32, 64);
      q += __shfl_xor(q, 16, 64); q += __shfl_xor(q, 32, 64);
      if ((lane >> 4) == 0 && col < EMBD){
        atomicAdd(&sred[col], s);
        atomicAdd(&sred[KEXT + col], q);
      }
    }
  }
  __syncthreads();
  for (int c = tid; c < EMBD; c += 256){
    atomicAdd(&stats[c], sred[c]);
    atomicAdd(&stats[EMBD + c], sred[KEXT + c]);
  }
}

__global__ void k_pool_bf(const bf16t* __restrict__ h, const int* __restrict__ offs,
                          const int* __restrict__ counts, const int* __restrict__ entries,
                          float* __restrict__ out, int M){
  int g = blockIdx.x, t = threadIdx.x, c1 = t + 256;
  int off = offs[g], cnt = counts[g];
  float a0 = 0.f, a1 = 0.f;
  for (int j = 0; j < cnt; j++){
    int r = entries[off + j];
    const bf16t* hr = h + (size_t)r*HROW;
    a0 += bf2f(hr[t]);
    if (c1 < EMBD) a1 += bf2f(hr[c1]);
  }
  float inv = 1.0f / fmaxf((float)cnt, 1.0f);
  float* o = out + (size_t)g*LDF;
  o[t] = a0*inv;
  if (c1 < EMBD) o[c1] = a1*inv;
}
__global__ void k_pool_f32(const float* __restrict__ h, const int* __restrict__ offs,
                           const int* __restrict__ counts, const int* __restrict__ entries,
                           float* __restrict__ out, int M){
  int g = blockIdx.x, t = threadIdx.x, c1 = t + 256;
  int off = offs[g], cnt = counts[g];
  float a0 = 0.f, a1 = 0.f;
  for (int j = 0; j < cnt; j++){
    int r = entries[off + j];
    const float* hr = h + (size_t)r*LDF;
    a0 += hr[t];
    if (c1 < EMBD) a1 += hr[c1];
  }
  float inv = 1.0f / fmaxf((float)cnt, 1.0f);
  float* o = out + (size_t)g*LDF;
  o[t] = a0*inv;
  if (c1 < EMBD) o[c1] = a1*inv;
}

// pooled rows: v = sc[c]*v + sh[c]  (last-layer BN folded past the mean-pool)
__global__ void k_affine_rows(float* __restrict__ rows, const float* __restrict__ coef, int M){
  int g = blockIdx.x, t = threadIdx.x, c1 = t + 256;
  float* r = rows + (size_t)g*LDF;
  r[t] = coef[t]*r[t] + coef[EMBD + t];
  if (c1 < EMBD) r[c1] = coef[c1]*r[c1] + coef[EMBD + c1];
}

__global__ void k_mask(float* __restrict__ j, const float* __restrict__ mask,
                       const float* __restrict__ memb, int M){
  int i = blockIdx.x;
  if (mask[i] <= 0.5f) return;
  int t = threadIdx.x, c1 = t + 256;
  float* jr = j + (size_t)i*LDF;
  jr[t] = memb[t];
  if (c1 < EMBD) jr[c1] = memb[c1];
}

__global__ void k_l2norm(float* __restrict__ f, int M){
  int g = blockIdx.x, t = threadIdx.x, c1 = t + 256;
  float* fr = f + (size_t)g*LDF;
  float v0 = fr[t];
  float v1 = (c1 < EMBD) ? fr[c1] : 0.f;
  float ss = v0*v0 + v1*v1;
  #pragma unroll
  for (int o = 32; o > 0; o >>= 1) ss += __shfl_down(ss, o, 64);
  __shared__ float red[4];
  int wid = t >> 6, lane = t & 63;
  if (lane == 0) red[wid] = ss;
  __syncthreads();
  if (t == 0) red[0] = 1.0f / fmaxf(sqrtf(red[0]+red[1]+red[2]+red[3]), 1e-12f);
  __syncthreads();
  float inv = red[0];
  fr[t] = v0*inv;
  if (c1 < EMBD) fr[c1] = v1*inv;
}

// fp32 GEMM for the small junction/logits matmuls
__global__ void __launch_bounds__(256)
k_gemm(const float* __restrict__ A, int lda, const float* __restrict__ W, int ldw,
       const float* __restrict__ bias, const float* __restrict__ e1, const float* __restrict__ e2,
       float* __restrict__ C, int ldc, int M, int Ncols, int K, int relu, float scale){
  __shared__ float As[16][68];
  __shared__ float Ws[16][68];
  int row0 = blockIdx.y * 64, col0 = blockIdx.x * 64;
  int tid = threadIdx.x;
  int tx = tid & 15, ty = tid >> 4;
  float acc[4][4] = {};
  for (int k0 = 0; k0 < K; k0 += 16){
    int r  = tid >> 2;
    int kk = (tid & 3) * 4;
    int gk = k0 + kk;
    float v[4] = {0.f,0.f,0.f,0.f};
    int gr = row0 + r;
    if (gr < M){
      if (gk + 3 < K){ float4 f = *(const float4*)(A + (size_t)gr*lda + gk); v[0]=f.x;v[1]=f.y;v[2]=f.z;v[3]=f.w; }
      else for (int j = 0; j < 4; j++) if (gk + j < K) v[j] = A[(size_t)gr*lda + gk + j];
    }
    As[kk+0][r]=v[0]; As[kk+1][r]=v[1]; As[kk+2][r]=v[2]; As[kk+3][r]=v[3];
    float w[4] = {0.f,0.f,0.f,0.f};
    int o = col0 + r;
    if (o < Ncols){
      if (gk + 3 < K){ float4 f = *(const float4*)(W + (size_t)o*ldw + gk); w[0]=f.x;w[1]=f.y;w[2]=f.z;w[3]=f.w; }
      else for (int j = 0; j < 4; j++) if (gk + j < K) w[j] = W[(size_t)o*ldw + gk + j];
    }
    Ws[kk+0][r]=w[0]; Ws[kk+1][r]=w[1]; Ws[kk+2][r]=w[2]; Ws[kk+3][r]=w[3];
    __syncthreads();
    #pragma unroll
    for (int k = 0; k < 16; k++){
      float4 a4 = *(const float4*)&As[k][ty*4];
      float4 b4 = *(const float4*)&Ws[k][tx*4];
      float a[4] = {a4.x,a4.y,a4.z,a4.w};
      float b[4] = {b4.x,b4.y,b4.z,b4.w};
      #pragma unroll
      for (int i = 0; i < 4; i++)
        #pragma unroll
        for (int j = 0; j < 4; j++) acc[i][j] += a[i]*b[j];
    }
    __syncthreads();
  }
  #pragma unroll
  for (int i = 0; i < 4; i++){
    int rr = row0 + ty*4 + i;
    if (rr >= M) continue;
    #pragma unroll
    for (int j = 0; j < 4; j++){
      int cc = col0 + tx*4 + j;
      if (cc >= Ncols) continue;
      float v = acc[i][j];
      if (bias) v += bias[cc];
      if (e1)   v += e1[cc];
      if (e2)   v += e2[cc];
      v *= scale;
      if (relu) v = fmaxf(v, 0.f);
      C[(size_t)rr*ldc + cc] = v;
    }
  }
}

// ---------------- host side ----------------
static inline void scan_excl(const int* counts, int M, int* offs, int* bsum, hipStream_t s){
  int B = CE(M, 256);
  k_scan_block<<<B,256,0,s>>>(counts, M, offs, bsum);
  k_scan_sums<<<1,1024,0,s>>>(bsum, B);
  k_scan_add<<<B,256,0,s>>>(offs, bsum, M);
}
static inline void gemm_f32(const float* A,int lda,const float* W,int ldw,
                            const float* bias,const float* e1,const float* e2,
                            float* C,int ldc,int M,int Ncols,int K,
                            int relu,float scale,hipStream_t s){
  dim3 grid(CE(Ncols,64), CE(M,64));
  k_gemm<<<grid,256,0,s>>>(A,lda,W,ldw,bias,e1,e2,C,ldc,M,Ncols,K,relu,scale);
}

extern "C" void kernel_launch(void* const* d_in, const int* in_sizes, int n_in,
                              void* d_out, int out_size, void* d_ws, size_t ws_size,
                              hipStream_t stream) {
  const int*   batch_x   = (const int*)d_in[0];
  const int*   batch_ei  = (const int*)d_in[1];
  const int*   batch_ea  = (const int*)d_in[2];
  const int*   batch_gid = (const int*)d_in[3];
  const int*   frag_x    = (const int*)d_in[4];
  const int*   frag_ei   = (const int*)d_in[5];
  const int*   frag_ea   = (const int*)d_in[6];
  const int*   frag_jid  = (const int*)d_in[7];
  const int*   jct_gid   = (const int*)d_in[8];
  const float* jct_mask  = (const float*)d_in[9];
  const float* ae1       = (const float*)d_in[10];
  const float* ae2       = (const float*)d_in[11];
  const float* gnn_W     = (const float*)d_in[12];
  const float* gnn_b     = (const float*)d_in[13];
  const float* gnn_ee1   = (const float*)d_in[14];
  const float* gnn_ee2   = (const float*)d_in[15];
  const float* bn_gamma  = (const float*)d_in[16];
  const float* bn_beta   = (const float*)d_in[17];
  const float* jct_W     = (const float*)d_in[18];
  const float* jct_b     = (const float*)d_in[19];
  const float* jct_ee1   = (const float*)d_in[20];
  const float* jct_ee2   = (const float*)d_in[21];
  const float* mask_emb  = (const float*)d_in[22];

  const int N = in_sizes[0] / 2;       // 200000
  const int E = in_sizes[1] / 2;       // 400000
  const int NG = 1024, NJ = 8192;

  // workspace carve-up (~249 MB)
  size_t off = 0;
  char* base = (char*)d_ws;
  auto carve = [&](size_t bytes) -> void* {
    void* p = base + off;
    off += (bytes + 255) & ~(size_t)255;
    return p;
  };
  bf16t* hA      = (bf16t*)carve((size_t)N * HROW * 2);
  bf16t* hB      = (bf16t*)carve((size_t)N * HROW * 2);
  float* dinv    = (float*)carve((size_t)N * 4);
  int*   degcnt  = (int*)  carve((size_t)N * 4);
  int*   cursor  = degcnt;                       // alias: dead after k_dinv
  int*   counts  = (int*)  carve((size_t)N * 4);
  int*   offs    = (int*)  carve((size_t)(N + 1) * 4);
  int*   entries = (int*)  carve((size_t)(E + N) * 4);
  int*   bsum    = (int*)  carve(1024 * 4);
  float* stats   = (float*)carve(2 * EMBD * 4);
  float* coef    = (float*)carve(2 * EMBD * 4);
  float* idcoef  = (float*)carve(2 * EMBD * 4);
  bf16t* wext    = (bf16t*)carve((size_t)5 * KEXT * KEXT * 2);
  float* f0      = (float*)carve((size_t)NG * LDF * 4);
  float* f1      = (float*)carve((size_t)NG * LDF * 4);
  size_t required = off;
  // junction-phase fp32 buffers alias hA (dead after the last k_layer reads it)
  float* g0      = (float*)hA;
  float* t1      = (float*)((char*)hA + ((size_t)16 << 20));
  float* t2      = (float*)((char*)hA + ((size_t)32 << 20));
  (void)n_in;

  if (ws_size < required || d_ws == nullptr){
    float v = 1.0e6f + (float)(ws_size >> 20) * 1000.0f;   // encode ws MB in absmax
    k_diag<<<CE(out_size,256),256,0,stream>>>((float*)d_out, out_size, v);
    return;
  }

  // one-time prep: extended bf16 weights, identity coef
  { dim3 g(KEXT, 5); k_wext<<<g,256,0,stream>>>(gnn_W, gnn_b, gnn_ee1, gnn_ee2, wext); }
  k_id_coef<<<CE(EMBD,256),256,0,stream>>>(idcoef);

  const int LBLK = CE(N, 64);   // fused-layer grid

  for (int br = 0; br < 2; br++){
    const int* x  = br ? frag_x  : batch_x;
    const int* ei = br ? frag_ei : batch_ei;
    const int* ea = br ? frag_ea : batch_ea;

    // degree (by src, +1 self-loop) -> dinv
    hipMemsetAsync(degcnt, 0, (size_t)N*4, stream);
    k_count_src<<<CE(E,256),256,0,stream>>>(ei, E, degcnt);
    k_dinv<<<CE(N,256),256,0,stream>>>(degcnt, dinv, N);

    // dst-CSR over E real edges + N self-loops (layer-invariant)
    k_set_val<<<CE(N,256),256,0,stream>>>(counts, N, 1);
    k_count_dst<<<CE(E,256),256,0,stream>>>(ei, E, counts);
    scan_excl(counts, N, offs, bsum, stream);
    hipMemsetAsync(cursor, 0, (size_t)N*4, stream);
    k_fill_edges<<<CE(E+N,256),256,0,stream>>>(ei, ea, E, N, offs, cursor, entries);

    // h0 = ae1[x0] + ae2[x1]
    k_init_h0<<<N,256,0,stream>>>(x, ae1, ae2, hA, N);

    // 5 fused layers, ping-pong hA <-> hB; final lin output lands in hB
    for (int l = 0; l < 5; l++){
      const bf16t* src = (l & 1) ? hB : hA;
      bf16t*       dst = (l & 1) ? hA : hB;
      hipMemsetAsync(stats, 0, 2*EMBD*4, stream);
      k_layer<<<LBLK,256,0,stream>>>(src, dinv, offs, counts, entries,
                                     wext + (size_t)l*KEXT*KEXT,
                                     (l == 0) ? idcoef : coef, dst,
                                     N, (l > 0) ? 1 : 0, stats);
      k_bn_coef<<<CE(EMBD,256),256,0,stream>>>(stats, bn_gamma + l*EMBD, bn_beta + l*EMBD,
                                               coef, 1.0f/(float)N);
    }
    // hB holds raw layer-4 lin output; coef holds its BN affine (no relu on last layer):
    // BN commutes with mean-pool -> apply affine on pooled rows.

    if (br == 0){
      hipMemsetAsync(counts, 0, (size_t)NG*4, stream);
      k_count_ids<<<CE(N,256),256,0,stream>>>(batch_gid, N, counts);
      scan_excl(counts, NG, offs, bsum, stream);
      hipMemsetAsync(cursor, 0, (size_t)NG*4, stream);
      k_fill_rows<<<CE(N,256),256,0,stream>>>(batch_gid, N, offs, cursor, entries);
      k_pool_bf<<<NG,256,0,stream>>>(hB, offs, counts, entries, g0, NG);
      k_affine_rows<<<NG,256,0,stream>>>(g0, coef, NG);
      gemm_f32(g0, LDF, jct_W, EMBD, jct_b,
               jct_ee1 + 4*EMBD, jct_ee2,
               t1, LDF, NG, EMBD, EMBD, 1, 1.0f, stream);
      gemm_f32(t1, LDF, jct_W + EMBD*EMBD, EMBD, jct_b + EMBD,
               jct_ee1 + 6*EMBD + 4*EMBD, jct_ee2 + 3*EMBD,
               f0, LDF, NG, EMBD, EMBD, 0, 1.0f, stream);
      k_l2norm<<<NG,256,0,stream>>>(f0, NG);
    } else {
      hipMemsetAsync(counts, 0, (size_t)NJ*4, stream);
      k_count_ids<<<CE(N,256),256,0,stream>>>(frag_jid, N, counts);
      scan_excl(counts, NJ, offs, bsum, stream);
      hipMemsetAsync(cursor, 0, (size_t)NJ*4, stream);
      k_fill_rows<<<CE(N,256),256,0,stream>>>(frag_jid, N, offs, cursor, entries);
      k_pool_bf<<<NJ,256,0,stream>>>(hB, offs, counts, entries, t1, NJ);
      k_affine_rows<<<NJ,256,0,stream>>>(t1, coef, NJ);
      k_mask<<<NJ,256,0,stream>>>(t1, jct_mask, mask_emb, NJ);
      gemm_f32(t1, LDF, jct_W, EMBD, jct_b,
               jct_ee1 + 4*EMBD, jct_ee2,
               t2, LDF, NJ, EMBD, EMBD, 1, 1.0f, stream);
      gemm_f32(t2, LDF, jct_W + EMBD*EMBD, EMBD, jct_b + EMBD,
               jct_ee1 + 6*EMBD + 4*EMBD, jct_ee2 + 3*EMBD,
               t1, LDF, NJ, EMBD, EMBD, 0, 1.0f, stream);
      hipMemsetAsync(counts, 0, (size_t)NG*4, stream);
      k_count_ids<<<CE(NJ,256),256,0,stream>>>(jct_gid, NJ, counts);
      scan_excl(counts, NG, offs, bsum, stream);
      hipMemsetAsync(cursor, 0, (size_t)NG*4, stream);
      k_fill_rows<<<CE(NJ,256),256,0,stream>>>(jct_gid, NJ, offs, cursor, entries);
      k_pool_f32<<<NG,256,0,stream>>>(t1, offs, counts, entries, f1, NG);
      k_l2norm<<<NG,256,0,stream>>>(f1, NG);
    }
  }

  // logits = (f0 @ f1^T) / TEMP
  gemm_f32(f0, LDF, f1, LDF, nullptr, nullptr, nullptr,
           (float*)d_out, 1024, NG, NG, EMBD, 0, 25.0f, stream);
}